// Round 8
// baseline (372.331 us; speedup 1.0000x reference)
//
#include <hip/hip_runtime.h>
#include <math.h>

#define NN 2048
#define NH 16
#define HSZ 32
#define INF_ 256
#define NBLK 256
#define NTHR 1024
#define NTOT (NBLK * NTHR)
#define DOOR_MAGIC 0x1357bd1

// bar slot indices (ints, 128B apart): 16 group counters, root, flag, doorbell
#define BAR_ROOT 512
#define BAR_FLAG 544
#define BAR_DOOR 576

struct Params {
    const float *x, *W1, *al1, *ar1, *bg1, *W2, *al2, *ar2, *bg2;
    const float *qw, *qb, *kw, *kb, *vw, *vb, *ow, *ob;
    const float *bn_g, *bn_b, *m1w, *m1b, *m2w, *m2b;
    const float *w001, *b001, *w01, *b01, *w1v, *b1v, *w2v, *b2v;
    const int *src, *dst;
    float *feat, *el, *er, *ssumA, *accA, *ssumB, *accB, *bnbuf, *KV, *out;
    int *bar;
    int E;
};

// agent-scope relaxed atomic store: sc1 write that bypasses L2 (never dirties
// it); visible at the coherence point once vmcnt retires (__syncthreads drains
// vmcnt per wave -> no release fence / buffer_wbl2 needed anywhere).
__device__ __forceinline__ void st_agent(float* p, float v) {
    __hip_atomic_store(p, v, __ATOMIC_RELAXED, __HIP_MEMORY_SCOPE_AGENT);
}

// Fence-free grid barrier (proven r7): monotonic 16x16 arrival tree of relaxed
// far-adds, relaxed poll on a separate line, per-wave ACQUIRE fence on exit
// (buffer_inv only) so plain cached loads are safe afterwards.
__device__ __forceinline__ void gbar(int* bar, int phase, bool first) {
    __syncthreads();  // drains vmcnt(0) per wave: all sc1 stores agent-visible
    if (threadIdx.x == 0) {
        if (first) {
            while (__hip_atomic_load(&bar[BAR_DOOR], __ATOMIC_RELAXED,
                                     __HIP_MEMORY_SCOPE_AGENT) != DOOR_MAGIC)
                __builtin_amdgcn_s_sleep(1);
        }
        int g = blockIdx.x & 15;
        int old = __hip_atomic_fetch_add(&bar[g * 32], 1, __ATOMIC_RELAXED,
                                         __HIP_MEMORY_SCOPE_AGENT);
        if (old == phase * 16 - 1) {  // last of my 16-block group this phase
            int r = __hip_atomic_fetch_add(&bar[BAR_ROOT], 1, __ATOMIC_RELAXED,
                                           __HIP_MEMORY_SCOPE_AGENT);
            if (r == phase * 16 - 1)
                __hip_atomic_store(&bar[BAR_FLAG], phase, __ATOMIC_RELAXED,
                                   __HIP_MEMORY_SCOPE_AGENT);
        }
        while (__hip_atomic_load(&bar[BAR_FLAG], __ATOMIC_RELAXED,
                                 __HIP_MEMORY_SCOPE_AGENT) < phase)
            __builtin_amdgcn_s_sleep(1);
    }
    __syncthreads();
    __builtin_amdgcn_fence(__ATOMIC_ACQUIRE, "agent");  // per-wave buffer_inv
}

// edge softmax-accumulate: thread per (edge,head), grid-stride, plain loads
__device__ __forceinline__ void edge_phase(const int* __restrict__ src,
                                           const int* __restrict__ dst,
                                           const float* __restrict__ el,
                                           const float* __restrict__ er,
                                           const float* __restrict__ feat,
                                           float* __restrict__ ssum,
                                           float* __restrict__ acc, int E, int gtid) {
    int EH = E * NH;
    for (int i = gtid; i < EH; i += NTOT) {
        int e = i >> 4, h = i & 15;
        int s = src[e], d = dst[e];
        float v = el[s * NH + h] + er[d * NH + h];
        v = v > 0.f ? v : 0.2f * v;
        float ex = __expf(v);
        float2 f = ((const float2*)feat)[s * NH + h];
        atomicAdd(&ssum[d * NH + h], ex);
        atomicAdd(&acc[(d * NH + h) * 2 + 0], ex * f.x);
        atomicAdd(&acc[(d * NH + h) * 2 + 1], ex * f.y);
    }
}

__global__ void __launch_bounds__(NTHR, 4) mega(Params p) {
    __shared__ float xs[2048];   // P0: 8 rows x 256 feats
    __shared__ float ps[1024];   // P0: 4-way K-split partials
    __shared__ float shH[256];   // staged h rows (8 x 32)
    __shared__ float shB[256];   // gemm out / X rows (persist P5->P6)
    __shared__ float shQ[256];   // Q rows (persist P4->P5)
    __shared__ float shO[256];   // attention output rows
    const int tid = threadIdx.x;
    const int blk = blockIdx.x;
    const int gtid = blk * NTHR + tid;
    const int row0 = blk * 8;

    // ---- barrier init (block 0; doorbell RELEASE last) ----
    if (blk == 0 && tid == 0) {
        for (int g = 0; g < 16; ++g)
            __hip_atomic_store(&p.bar[g * 32], 0, __ATOMIC_RELAXED,
                               __HIP_MEMORY_SCOPE_AGENT);
        __hip_atomic_store(&p.bar[BAR_ROOT], 0, __ATOMIC_RELAXED,
                           __HIP_MEMORY_SCOPE_AGENT);
        __hip_atomic_store(&p.bar[BAR_FLAG], 0, __ATOMIC_RELAXED,
                           __HIP_MEMORY_SCOPE_AGENT);
        __hip_atomic_store(&p.bar[BAR_DOOR], DOOR_MAGIC, __ATOMIC_RELEASE,
                           __HIP_MEMORY_SCOPE_AGENT);
    }

    // ---- P0: zero accumulators (sc1) + GAT1 feats (8 rows, 4-way K-split) ----
    {
        float* z = p.ssumA;
        const int ztot = NN * 96 + 64;
        for (int i = gtid; i < ztot; i += NTOT) st_agent(&z[i], 0.f);
    }
    xs[tid] = p.x[(size_t)row0 * INF_ + tid];
    xs[tid + 1024] = p.x[(size_t)row0 * INF_ + 1024 + tid];
    __syncthreads();
    {
        int out = tid & 255, part = tid >> 8;
        int rr = out >> 5, jj = out & 31;
        float a = 0.f;
#pragma unroll
        for (int kk = 0; kk < 64; ++kk) {
            int k = part * 64 + kk;
            a += xs[rr * 256 + k] * p.W1[k * HSZ + jj];
        }
        ps[tid] = a;
    }
    __syncthreads();
    if (tid < 256) {
        float s = ps[tid] + ps[tid + 256] + ps[tid + 512] + ps[tid + 768];
        st_agent(&p.feat[row0 * HSZ + tid], s);
        shH[tid] = s;
    }
    __syncthreads();
    if (tid < 128) {
        int rr = tid >> 4, hh = tid & 15;
        st_agent(&p.el[(row0 + rr) * NH + hh],
                 shH[rr * HSZ + 2 * hh] * p.al1[2 * hh] +
                     shH[rr * HSZ + 2 * hh + 1] * p.al1[2 * hh + 1]);
    } else if (tid < 256) {
        int t = tid - 128, rr = t >> 4, hh = t & 15;
        st_agent(&p.er[(row0 + rr) * NH + hh],
                 shH[rr * HSZ + 2 * hh] * p.ar1[2 * hh] +
                     shH[rr * HSZ + 2 * hh + 1] * p.ar1[2 * hh + 1]);
    }
    gbar(p.bar, 1, true);

    // ---- P1: edge accumulate, layer 1 ----
    edge_phase(p.src, p.dst, p.el, p.er, p.feat, p.ssumA, p.accA, p.E, gtid);
    gbar(p.bar, 2, false);

    // ---- P2: normalize h1 -> GAT2 feats ----
    if (tid < 256) {
        int rr = tid >> 5, jj = tid & 31;
        int n = row0 + rr;
        shH[tid] = p.accA[n * HSZ + jj] / p.ssumA[n * NH + (jj >> 1)] + p.bg1[jj];
    }
    __syncthreads();
    if (tid < 256) {
        int rr = tid >> 5, jj = tid & 31;
        float a = 0.f;
#pragma unroll
        for (int c = 0; c < HSZ; ++c) a += shH[rr * HSZ + c] * p.W2[c * HSZ + jj];
        shB[tid] = a;
        st_agent(&p.feat[row0 * HSZ + tid], a);
    }
    __syncthreads();
    if (tid < 128) {
        int rr = tid >> 4, hh = tid & 15;
        st_agent(&p.el[(row0 + rr) * NH + hh],
                 shB[rr * HSZ + 2 * hh] * p.al2[2 * hh] +
                     shB[rr * HSZ + 2 * hh + 1] * p.al2[2 * hh + 1]);
    } else if (tid < 256) {
        int t = tid - 128, rr = t >> 4, hh = t & 15;
        st_agent(&p.er[(row0 + rr) * NH + hh],
                 shB[rr * HSZ + 2 * hh] * p.ar2[2 * hh] +
                     shB[rr * HSZ + 2 * hh + 1] * p.ar2[2 * hh + 1]);
    }
    gbar(p.bar, 3, false);

    // ---- P3: edge accumulate, layer 2 ----
    edge_phase(p.src, p.dst, p.el, p.er, p.feat, p.ssumB, p.accB, p.E, gtid);
    gbar(p.bar, 4, false);

    // ---- P4: h2 -> QKV. Q stays in LDS; K,V packed float4 (sc1) ----
    if (tid < 256) {
        int rr = tid >> 5, jj = tid & 31;
        int n = row0 + rr;
        shH[tid] = p.accB[n * HSZ + jj] / p.ssumB[n * NH + (jj >> 1)] + p.bg2[jj];
    }
    __syncthreads();
    if (tid < 256) {
        int rr = tid >> 5, jj = tid & 31;
        int n = row0 + rr;
        float q = p.qb[jj], k = p.kb[jj], v = p.vb[jj];
#pragma unroll
        for (int c = 0; c < HSZ; ++c) {
            float hv = shH[rr * HSZ + c];
            q += hv * p.qw[c * HSZ + jj];
            k += hv * p.kw[c * HSZ + jj];
            v += hv * p.vw[c * HSZ + jj];
        }
        shQ[tid] = q * 0.70710678118654752f;
        int hh = jj >> 1, d2 = jj & 1;
        st_agent(&p.KV[(hh * NN + n) * 4 + d2], k);
        st_agent(&p.KV[(hh * NN + n) * 4 + 2 + d2], v);
    }
    gbar(p.bar, 5, false);

    // ---- P5: attention — 16 waves = 16 heads concurrently, 8 queries each;
    //          then O-projection + BN partial sums. KV via plain cached float4.
    {
        int h = tid >> 6, lane = tid & 63;
        float qx[8], qy[8];
#pragma unroll
        for (int i = 0; i < 8; ++i) {
            qx[i] = shQ[i * HSZ + 2 * h];
            qy[i] = shQ[i * HSZ + 2 * h + 1];
        }
        const float4* KV4 = (const float4*)p.KV + h * NN;
        float sm[8], a0[8], a1[8];
#pragma unroll
        for (int i = 0; i < 8; ++i) { sm[i] = 0.f; a0[i] = 0.f; a1[i] = 0.f; }
#pragma unroll 2
        for (int it = 0; it < NN / 64; ++it) {
            float4 kv = KV4[it * 64 + lane];
#pragma unroll
            for (int i = 0; i < 8; ++i) {
                float pp = __expf(qx[i] * kv.x + qy[i] * kv.y);
                sm[i] += pp;
                a0[i] += pp * kv.z;
                a1[i] += pp * kv.w;
            }
        }
#pragma unroll
        for (int i = 0; i < 8; ++i) {
#pragma unroll
            for (int off = 32; off > 0; off >>= 1) {
                sm[i] += __shfl_xor(sm[i], off);
                a0[i] += __shfl_xor(a0[i], off);
                a1[i] += __shfl_xor(a1[i], off);
            }
            if (lane == 0) {
                float rs = 1.f / sm[i];
                shO[i * HSZ + 2 * h] = a0[i] * rs;
                shO[i * HSZ + 2 * h + 1] = a1[i] * rs;
            }
        }
    }
    __syncthreads();
    if (tid < 256) {
        int rr = tid >> 5, jj = tid & 31;
        float a = p.ob[jj];
#pragma unroll
        for (int c = 0; c < HSZ; ++c) a += shO[rr * HSZ + c] * p.ow[c * HSZ + jj];
        shB[tid] = a;  // X rows stay in LDS for P6
    }
    __syncthreads();
    if (tid < HSZ) {
        float s = 0.f, q = 0.f;
#pragma unroll
        for (int rr = 0; rr < 8; ++rr) {
            float v = shB[rr * HSZ + tid];
            s += v;
            q += v * v;
        }
        atomicAdd(&p.bnbuf[tid], s);
        atomicAdd(&p.bnbuf[HSZ + tid], q);
    }
    gbar(p.bar, 6, false);

    // ---- P6: BN apply + MLP + scoring head + sigmoid (rows from LDS shB) ----
    if (tid < 8) {
        int row = tid;
        const float invN = 1.f / NN;
        float xr[HSZ];
#pragma unroll
        for (int i = 0; i < HSZ; ++i) {
            float mu = p.bnbuf[i] * invN;
            float var = p.bnbuf[HSZ + i] * invN - mu * mu;
            float rstd = rsqrtf(var + 1e-5f);
            xr[i] = (shB[row * HSZ + i] - mu) * rstd * p.bn_g[i] + p.bn_b[i];
        }
        float y[16];
#pragma unroll
        for (int jj = 0; jj < 16; ++jj) {
            float a = p.m1b[jj];
#pragma unroll
            for (int i = 0; i < HSZ; ++i) a += xr[i] * p.m1w[i * 16 + jj];
            y[jj] = fmaxf(a, 0.f);
        }
        float z[HSZ];
#pragma unroll
        for (int jj = 0; jj < HSZ; ++jj) {
            float a = p.m2b[jj];
#pragma unroll
            for (int i = 0; i < 16; ++i) a += y[i] * p.m2w[i * HSZ + jj];
            z[jj] = fmaxf(a, 0.f);
        }
        float a16[16];
#pragma unroll
        for (int jj = 0; jj < 16; ++jj) {
            float a = p.b001[jj];
#pragma unroll
            for (int i = 0; i < HSZ; ++i) a += z[i] * p.w001[i * 16 + jj];
            a16[jj] = a > 0.f ? a : 0.01f * a;
        }
        float b8[8];
#pragma unroll
        for (int jj = 0; jj < 8; ++jj) {
            float a = p.b01[jj];
#pragma unroll
            for (int i = 0; i < 16; ++i) a += a16[i] * p.w01[i * 8 + jj];
            b8[jj] = a > 0.f ? a : 0.01f * a;
        }
        float c4[4];
#pragma unroll
        for (int jj = 0; jj < 4; ++jj) {
            float a = p.b1v[jj];
#pragma unroll
            for (int i = 0; i < 8; ++i) a += b8[i] * p.w1v[i * 4 + jj];
            c4[jj] = a > 0.f ? a : 0.01f * a;
        }
        float d = p.b2v[0];
#pragma unroll
        for (int i = 0; i < 4; ++i) d += c4[i] * p.w2v[i];
        p.out[row0 + row] = 1.f / (1.f + __expf(-d));
    }
}

extern "C" void kernel_launch(void* const* d_in, const int* in_sizes, int n_in,
                              void* d_out, int out_size, void* d_ws, size_t ws_size,
                              hipStream_t stream) {
    Params p;
    p.x = (const float*)d_in[0];
    p.src = (const int*)d_in[1];
    p.dst = (const int*)d_in[2];
    p.W1 = (const float*)d_in[3];
    p.al1 = (const float*)d_in[4];
    p.ar1 = (const float*)d_in[5];
    p.bg1 = (const float*)d_in[6];
    p.W2 = (const float*)d_in[7];
    p.al2 = (const float*)d_in[8];
    p.ar2 = (const float*)d_in[9];
    p.bg2 = (const float*)d_in[10];
    p.qw = (const float*)d_in[11];
    p.qb = (const float*)d_in[12];
    p.kw = (const float*)d_in[13];
    p.kb = (const float*)d_in[14];
    p.vw = (const float*)d_in[15];
    p.vb = (const float*)d_in[16];
    p.ow = (const float*)d_in[17];
    p.ob = (const float*)d_in[18];
    p.bn_g = (const float*)d_in[19];
    p.bn_b = (const float*)d_in[20];
    p.m1w = (const float*)d_in[21];
    p.m1b = (const float*)d_in[22];
    p.m2w = (const float*)d_in[23];
    p.m2b = (const float*)d_in[24];
    p.w001 = (const float*)d_in[25];
    p.b001 = (const float*)d_in[26];
    p.w01 = (const float*)d_in[27];
    p.b01 = (const float*)d_in[28];
    p.w1v = (const float*)d_in[29];
    p.b1v = (const float*)d_in[30];
    p.w2v = (const float*)d_in[31];
    p.b2v = (const float*)d_in[32];
    p.E = in_sizes[1];

    float* ws = (float*)d_ws;
    p.feat = ws;                       // NN*32
    p.el = p.feat + NN * HSZ;          // NN*16
    p.er = p.el + NN * NH;             // NN*16
    p.ssumA = p.er + NN * NH;          // NN*16 ┐ zeroed as one
    p.accA = p.ssumA + NN * NH;        // NN*32 │ contiguous
    p.ssumB = p.accA + NN * HSZ;       // NN*16 │ region in P0
    p.accB = p.ssumB + NN * NH;        // NN*32 │
    p.bnbuf = p.accB + NN * HSZ;       // 64    ┘
    p.KV = p.bnbuf + 64;               // NH*NN*4 (k0,k1,v0,v1 per key)
    p.bar = (int*)(p.KV + NH * NN * 4);  // 577 ints, 128B-spaced slots
    p.out = (float*)d_out;

    mega<<<dim3(NBLK), dim3(NTHR), 0, stream>>>(p);
}